// Round 6
// baseline (640.741 us; speedup 1.0000x reference)
//
#include <hip/hip_runtime.h>
#include <hip/hip_bf16.h>
#include <cstdint>
#include <cstddef>

typedef __bf16 bf16;
typedef __bf16 bf16x8 __attribute__((ext_vector_type(8)));
typedef float f32x4 __attribute__((ext_vector_type(4)));

#define N_PTS 131072
#define CDIM  512
#define C3    1536
#define HD    64
#define NH    8
#define KWIN  128

static __device__ __forceinline__ bf16 cvt(float x) { return (bf16)x; }

// async global->LDS, 16B per lane. LDS dest = wave-uniform base + lane*16.
static __device__ __forceinline__ void gld16(const bf16* g, bf16* l) {
    __builtin_amdgcn_global_load_lds(
        (const __attribute__((address_space(1))) void*)g,
        (__attribute__((address_space(3))) void*)l, 16, 0, 0);
}

// ---------------------------------------------------------------------------
// Weight prep: transpose + cast f32 -> bf16.  Wt[col][k] = W[k][col].
// ---------------------------------------------------------------------------
__global__ __launch_bounds__(256) void k_prep(
    const float* __restrict__ Wqkv, const float* __restrict__ Wproj,
    bf16* __restrict__ Wqkv_t, bf16* __restrict__ Wproj_t)
{
    int idx = blockIdx.x * 256 + threadIdx.x;
    if (idx < CDIM * C3) {
        int k = idx / C3, c = idx % C3;
        Wqkv_t[(size_t)c * CDIM + k] = cvt(Wqkv[idx]);
    } else {
        int j = idx - CDIM * C3;
        if (j < CDIM * CDIM) {
            int k = j / CDIM, c = j % CDIM;
            Wproj_t[(size_t)c * CDIM + k] = cvt(Wproj[j]);
        }
    }
}

// ---------------------------------------------------------------------------
// Gather + cast: feat_g[i][:] = bf16(feat[order[i]][:])
// ---------------------------------------------------------------------------
__global__ __launch_bounds__(256) void k_gather(
    const float* __restrict__ feat, const int* __restrict__ order,
    bf16* __restrict__ feat_g)
{
    int row = blockIdx.x * 2 + (threadIdx.x >> 7);
    int c   = (threadIdx.x & 127) << 2;
    int src = order[row];
    float4 v = *reinterpret_cast<const float4*>(feat + (size_t)src * CDIM + c);
    union { bf16 e[4]; uint2 u; } pk;
    pk.e[0] = cvt(v.x); pk.e[1] = cvt(v.y); pk.e[2] = cvt(v.z); pk.e[3] = cvt(v.w);
    *reinterpret_cast<uint2*>(feat_g + (size_t)row * CDIM + c) = pk.u;
}

// ---------------------------------------------------------------------------
// Phase-split bf16 GEMM (T3+T4+T5: 2 phases/K-step, counted vmcnt, setprio):
//   out[m, n] = A[m, :] @ Bt[n, :]^T + bias[n]
// 256x256 tile, BK=32, 8 waves (2M x 4N), wave owns 128x64 C (8x4 frags,
// acc = 128 AGPR). 3-deep LDS ring: 3 x (A 16KB + B 16KB) = 96 KB, 1 blk/CU.
//
// Per K-step s (buffer s%3), two phases:
//  P1: ds_read A-frags 0-3 + B-frags 0-3 (8 b128) | stage A of s+2 (2 gld16)
//      -> barrier -> lgkm(0)+sched_barrier -> 16 MFMA (m0-3 x n0-3) -> barrier
//  P2: ds_read A-frags 4-7 (4 b128)              | stage B of s+2 (2 gld16)
//      -> barrier -> lgkm(0)+sched_barrier -> 16 MFMA (m4-7 x n0-3)
//      -> vmcnt(4) [confirms step s+1; s+2's 4 stay in flight] -> barrier
//
// WAR safety: buf (s+2)%3's last readers (step s-1) completed at step s-1's
// lgkm(0), which precedes the closing barrier that step s's gld16s sit behind
// (per-wave in-order issue + sched_barrier pins against compiler motion).
// RAW safety: step s's buffer was staged in step s-2, confirmed by vmcnt(4)
// at end of step s-1 + barrier.
//
// LDS rotate-permute layout (verified R4/R5: SQ_LDS_BANK_CONFLICT = 0):
// chunk (row*4+p) holds k-slot (p-(row>>1))&3; reader byte =
// row*64 + (((g+(row>>1))&3)<<4); staging inversely permutes the per-lane
// GLOBAL source; LDS dest stays linear for global_load_lds.
// ---------------------------------------------------------------------------
template <bool F32OUT, int NT>
__global__ __launch_bounds__(512, 2) void k_gemm(
    const bf16* __restrict__ Ag, const bf16* __restrict__ Bt,
    const float* __restrict__ bias, void* __restrict__ outp)
{
    __shared__ __align__(16) bf16 As[3][256 * 32];
    __shared__ __align__(16) bf16 Bs[3][256 * 32];

    const int t    = threadIdx.x;
    const int lane = t & 63;
    const int wv   = t >> 6;          // 0..7
    const int wr   = wv >> 2;         // 0..1  (M half: 128 rows)
    const int wc   = wv & 3;          // 0..3  (N quarter: 64 cols)
    const int g    = lane >> 4, r16 = lane & 15;

    const int nwg = gridDim.x;
    const int bid = blockIdx.x;
    const int swz = (bid & 7) * (nwg >> 3) + (bid >> 3);  // grids are %8==0
    const int m0  = (swz / NT) * 256;
    const int n0  = (swz % NT) * 256;

    // staging: thread owns linear 16B chunks L0 (0..511) and L0+512 of each
    // operand tile. chunk L: row=L>>2, phys slot p=L&3, src k-slot=(p-(row>>1))&3.
    const int L0 = wv * 64 + lane;
    const int r0 = L0 >> 2,        s0 = ((L0 & 3) - (r0 >> 1)) & 3;
    const int r1 = r0 + 128,       s1 = ((L0 & 3) - (r1 >> 1)) & 3;
    const bf16* srcA0 = Ag + (size_t)(m0 + r0) * CDIM + s0 * 8;
    const bf16* srcA1 = Ag + (size_t)(m0 + r1) * CDIM + s1 * 8;
    const bf16* srcB0 = Bt + (size_t)(n0 + r0) * CDIM + s0 * 8;
    const bf16* srcB1 = Bt + (size_t)(n0 + r1) * CDIM + s1 * 8;

    // fragment read byte-offsets (rotate-permuted slots)
    int aoff[8], boff[4];
#pragma unroll
    for (int i = 0; i < 8; ++i) {
        int row = wr * 128 + i * 16 + r16;
        aoff[i] = row * 64 + (((g + (row >> 1)) & 3) << 4);
    }
#pragma unroll
    for (int n = 0; n < 4; ++n) {
        int row = wc * 64 + n * 16 + r16;
        boff[n] = row * 64 + (((g + (row >> 1)) & 3) << 4);
    }

    f32x4 acc[8][4];
    const f32x4 z = {0.f, 0.f, 0.f, 0.f};
#pragma unroll
    for (int i = 0; i < 8; ++i)
#pragma unroll
        for (int n = 0; n < 4; ++n) acc[i][n] = z;

    const int NKT = CDIM / 32;   // 16

    auto stageA = [&](int s) {
        const int b  = s % 3;
        const int ko = s * 32;
        gld16(srcA0 + ko, &As[b][(size_t)wv * 64 * 8]);
        gld16(srcA1 + ko, &As[b][(size_t)(512 + wv * 64) * 8]);
    };
    auto stageB = [&](int s) {
        const int b  = s % 3;
        const int ko = s * 32;
        gld16(srcB0 + ko, &Bs[b][(size_t)wv * 64 * 8]);
        gld16(srcB1 + ko, &Bs[b][(size_t)(512 + wv * 64) * 8]);
    };

    // prologue: stage steps 0 and 1; confirm step 0 (step 1's 4 in flight)
    stageA(0); stageB(0); stageA(1); stageB(1);
    asm volatile("s_waitcnt vmcnt(4)" ::: "memory");
    __builtin_amdgcn_s_barrier();
    __builtin_amdgcn_sched_barrier(0);

#pragma unroll
    for (int s = 0; s < NKT; ++s) {
        const int b = s % 3;
        const char* abase = reinterpret_cast<const char*>(&As[b][0]);
        const char* bbase = reinterpret_cast<const char*>(&Bs[b][0]);

        // ---- phase 1: A-frags 0-3 + B-frags 0-3, stage A(s+2), MFMA q0 ----
        bf16x8 af0[4], bv[4];
#pragma unroll
        for (int i = 0; i < 4; ++i)
            af0[i] = *reinterpret_cast<const bf16x8*>(abase + aoff[i]);
#pragma unroll
        for (int n = 0; n < 4; ++n)
            bv[n] = *reinterpret_cast<const bf16x8*>(bbase + boff[n]);
        if (s < NKT - 2) stageA(s + 2);
        __builtin_amdgcn_s_barrier();
        asm volatile("s_waitcnt lgkmcnt(0)" ::: "memory");
        __builtin_amdgcn_sched_barrier(0);
        __builtin_amdgcn_s_setprio(1);
#pragma unroll
        for (int i = 0; i < 4; ++i)
#pragma unroll
            for (int n = 0; n < 4; ++n)
                acc[i][n] = __builtin_amdgcn_mfma_f32_16x16x32_bf16(
                    af0[i], bv[n], acc[i][n], 0, 0, 0);
        __builtin_amdgcn_s_setprio(0);
        __builtin_amdgcn_s_barrier();
        __builtin_amdgcn_sched_barrier(0);

        // ---- phase 2: A-frags 4-7 (B reused), stage B(s+2), MFMA q1 ----
        bf16x8 af1[4];
#pragma unroll
        for (int i = 0; i < 4; ++i)
            af1[i] = *reinterpret_cast<const bf16x8*>(abase + aoff[4 + i]);
        if (s < NKT - 2) stageB(s + 2);
        __builtin_amdgcn_s_barrier();
        asm volatile("s_waitcnt lgkmcnt(0)" ::: "memory");
        __builtin_amdgcn_sched_barrier(0);
        __builtin_amdgcn_s_setprio(1);
#pragma unroll
        for (int i = 0; i < 4; ++i)
#pragma unroll
            for (int n = 0; n < 4; ++n)
                acc[4 + i][n] = __builtin_amdgcn_mfma_f32_16x16x32_bf16(
                    af1[i], bv[n], acc[4 + i][n], 0, 0, 0);
        __builtin_amdgcn_s_setprio(0);
        if (s < NKT - 2)
            asm volatile("s_waitcnt vmcnt(4)" ::: "memory");  // step s+1 resident
        else if (s == NKT - 2)
            asm volatile("s_waitcnt vmcnt(0)" ::: "memory");  // last step resident
        __builtin_amdgcn_s_barrier();
        __builtin_amdgcn_sched_barrier(0);
    }

    // epilogue: D layout col=lane&15, row=(lane>>4)*4+j
    const int ldo = NT * 256;
#pragma unroll
    for (int n = 0; n < 4; ++n) {
        int col = n0 + wc * 64 + n * 16 + r16;
        float b = bias[col];
#pragma unroll
        for (int i = 0; i < 8; ++i)
#pragma unroll
            for (int j = 0; j < 4; ++j) {
                int row = m0 + wr * 128 + i * 16 + g * 4 + j;
                if (F32OUT)
                    reinterpret_cast<float*>(outp)[(size_t)row * ldo + col] =
                        acc[i][n][j] + b;
                else
                    reinterpret_cast<bf16*>(outp)[(size_t)row * ldo + col] =
                        cvt(acc[i][n][j] + b);
            }
    }
}

// ---------------------------------------------------------------------------
// Attention: one block per (window, head). 4 waves, each owns 32 query rows.
// Output rows are SCATTERED to attn_g[order[w*128+tok]] so that k_proj's A
// operand is sequential (order[inverse[n]] == n).
// ---------------------------------------------------------------------------
__global__ __launch_bounds__(256) void k_attn(
    const bf16* __restrict__ qkv_s, const int* __restrict__ order,
    bf16* __restrict__ attn_g)
{
    __shared__ __align__(16) char smem[36864 + 64 * 136 * 2];
    __shared__ int ord_s[KWIN];
    bf16 (*Q)[72]   = reinterpret_cast<bf16 (*)[72]>(smem);
    bf16 (*Kt)[72]  = reinterpret_cast<bf16 (*)[72]>(smem + 128 * 72 * 2);
    bf16 (*P)[136]  = reinterpret_cast<bf16 (*)[136]>(smem);          // overlaps Q,K
    bf16 (*Vt)[136] = reinterpret_cast<bf16 (*)[136]>(smem + 36864);  // V transposed

    const int t    = threadIdx.x;
    const int lane = t & 63;
    const int wv   = t >> 6;
    const int g    = lane >> 4, r16 = lane & 15;
    const int h    = blockIdx.x;
    const int w    = blockIdx.y;

    const bf16* base = qkv_s + (size_t)w * KWIN * C3 + h * HD;

    if (t < KWIN) ord_s[t] = order[w * KWIN + t];

    // stage Q, K (row-major [tok][d]) and V transposed [d][tok]
#pragma unroll
    for (int it = 0; it < 4; ++it) {
        int s   = it * 256 + t;      // 0..1023
        int tok = s >> 3;
        int c8  = (s & 7) << 3;
        size_t roff = (size_t)tok * C3 + c8;
        *reinterpret_cast<uint4*>(&Q[tok][c8])  =
            *reinterpret_cast<const uint4*>(base + roff);
        *reinterpret_cast<uint4*>(&Kt[tok][c8]) =
            *reinterpret_cast<const uint4*>(base + roff + CDIM);
        uint4 vvec = *reinterpret_cast<const uint4*>(base + roff + 2 * CDIM);
        const bf16* ve = reinterpret_cast<const bf16*>(&vvec);
#pragma unroll
        for (int i = 0; i < 8; ++i) Vt[c8 + i][tok] = ve[i];
    }
    __syncthreads();

    // S = Q K^T for rows [wv*32, wv*32+32)
    f32x4 sc[2][8];
    const f32x4 z = {0.f, 0.f, 0.f, 0.f};
#pragma unroll
    for (int m = 0; m < 2; ++m)
#pragma unroll
        for (int n = 0; n < 8; ++n) sc[m][n] = z;

#pragma unroll
    for (int ks = 0; ks < 2; ++ks) {
        bf16x8 aq[2];
#pragma unroll
        for (int m = 0; m < 2; ++m)
            aq[m] = *reinterpret_cast<const bf16x8*>(
                &Q[wv * 32 + m * 16 + r16][ks * 32 + g * 8]);
#pragma unroll
        for (int n = 0; n < 8; ++n) {
            bf16x8 bk = *reinterpret_cast<const bf16x8*>(
                &Kt[n * 16 + r16][ks * 32 + g * 8]);
#pragma unroll
            for (int m = 0; m < 2; ++m)
                sc[m][n] = __builtin_amdgcn_mfma_f32_16x16x32_bf16(
                    aq[m], bk, sc[m][n], 0, 0, 0);
        }
    }

    // softmax (f32), row-parallel over 16-lane groups
    const float scale = 0.125f;   // hd^-0.5
    float inv_sum[2][4];
#pragma unroll
    for (int m = 0; m < 2; ++m) {
#pragma unroll
        for (int j = 0; j < 4; ++j) {
            float mx = -3.0e38f;
#pragma unroll
            for (int n = 0; n < 8; ++n) mx = fmaxf(mx, sc[m][n][j]);
            mx = fmaxf(mx, __shfl_xor(mx, 1));
            mx = fmaxf(mx, __shfl_xor(mx, 2));
            mx = fmaxf(mx, __shfl_xor(mx, 4));
            mx = fmaxf(mx, __shfl_xor(mx, 8));
            mx *= scale;
            float ssum = 0.f;
#pragma unroll
            for (int n = 0; n < 8; ++n) {
                float p = __expf(sc[m][n][j] * scale - mx);
                sc[m][n][j] = p;
                ssum += p;
            }
            ssum += __shfl_xor(ssum, 1);
            ssum += __shfl_xor(ssum, 2);
            ssum += __shfl_xor(ssum, 4);
            ssum += __shfl_xor(ssum, 8);
            inv_sum[m][j] = 1.f / ssum;
        }
    }

    __syncthreads();   // all waves done reading Q/Kt before P overwrites them

    // write normalized P (bf16)
#pragma unroll
    for (int m = 0; m < 2; ++m)
#pragma unroll
        for (int n = 0; n < 8; ++n)
#pragma unroll
            for (int j = 0; j < 4; ++j)
                P[wv * 32 + m * 16 + g * 4 + j][n * 16 + r16] =
                    cvt(sc[m][n][j] * inv_sum[m][j]);

    // O = P V   (32x64 per wave)
    f32x4 o[2][4];
#pragma unroll
    for (int m = 0; m < 2; ++m)
#pragma unroll
        for (int n = 0; n < 4; ++n) o[m][n] = z;

#pragma unroll
    for (int kt = 0; kt < 4; ++kt) {
        bf16x8 ap[2];
#pragma unroll
        for (int m = 0; m < 2; ++m)
            ap[m] = *reinterpret_cast<const bf16x8*>(
                &P[wv * 32 + m * 16 + r16][kt * 32 + g * 8]);
#pragma unroll
        for (int n = 0; n < 4; ++n) {
            bf16x8 bv = *reinterpret_cast<const bf16x8*>(
                &Vt[n * 16 + r16][kt * 32 + g * 8]);
#pragma unroll
            for (int m = 0; m < 2; ++m)
                o[m][n] = __builtin_amdgcn_mfma_f32_16x16x32_bf16(
                    ap[m], bv, o[m][n], 0, 0, 0);
        }
    }

    // scatter rows to unserialized position: attn_g[order[i]] = ser[i]
#pragma unroll
    for (int m = 0; m < 2; ++m)
#pragma unroll
        for (int n = 0; n < 4; ++n)
#pragma unroll
            for (int j = 0; j < 4; ++j) {
                int tok  = wv * 32 + m * 16 + g * 4 + j;
                int d    = n * 16 + r16;
                int drow = ord_s[tok];
                attn_g[(size_t)drow * CDIM + h * HD + d] = cvt(o[m][n][j]);
            }
}

// ---------------------------------------------------------------------------
extern "C" void kernel_launch(void* const* d_in, const int* in_sizes, int n_in,
                              void* d_out, int out_size, void* d_ws, size_t ws_size,
                              hipStream_t stream)
{
    const float* feat    = (const float*)d_in[0];
    const float* Wqkv    = (const float*)d_in[1];
    const float* bqkv    = (const float*)d_in[2];
    const float* Wproj   = (const float*)d_in[3];
    const float* bproj   = (const float*)d_in[4];
    const int*   order   = (const int*)d_in[5];
    float* out = (float*)d_out;

    const size_t qkv_bytes  = (size_t)N_PTS * C3 * sizeof(bf16);    // 402.7 MB
    const size_t gat_bytes  = (size_t)N_PTS * CDIM * sizeof(bf16);  // 134.2 MB (feat_g / attn_g)
    const size_t wq_bytes   = (size_t)C3 * CDIM * sizeof(bf16);
    const size_t wp_bytes   = (size_t)CDIM * CDIM * sizeof(bf16);
    if (ws_size < qkv_bytes + gat_bytes + wq_bytes + wp_bytes) return;

    bf16* qkv_s     = (bf16*)d_ws;
    bf16* shared134 = (bf16*)((char*)d_ws + qkv_bytes);   // feat_g, later attn_g
    bf16* Wqkv_t    = (bf16*)((char*)d_ws + qkv_bytes + gat_bytes);
    bf16* Wproj_t   = (bf16*)((char*)d_ws + qkv_bytes + gat_bytes + wq_bytes);

    k_prep<<<dim3((CDIM * C3 + CDIM * CDIM + 255) / 256), 256, 0, stream>>>(
        Wqkv, Wproj, Wqkv_t, Wproj_t);
    k_gather<<<dim3(N_PTS / 2), 256, 0, stream>>>(feat, order, shared134);
    // qkv GEMM: [131072 x 1536] = feat_g @ Wqkv_t^T  (512 x 6 = 3072 blocks)
    k_gemm<false, C3 / 256><<<dim3((N_PTS / 256) * (C3 / 256)), 512, 0, stream>>>(
        shared134, Wqkv_t, bqkv, qkv_s);
    // attention (reads qkv_s, scatters into shared134 = attn_g)
    k_attn<<<dim3(NH, N_PTS / KWIN), 256, 0, stream>>>(qkv_s, order, shared134);
    // proj GEMM: [131072 x 512] = attn_g @ Wproj_t^T  (512 x 2 = 1024 blocks)
    k_gemm<true, CDIM / 256><<<dim3((N_PTS / 256) * (CDIM / 256)), 512, 0, stream>>>(
        shared134, Wproj_t, bproj, out);
}